// Round 11
// baseline (142.689 us; speedup 1.0000x reference)
//
#include <hip/hip_runtime.h>
#include <hip/hip_bf16.h>

#define B_ROWS 4096
#define NROWS  8192   // 2B
#define D      256
#define NSEG   48     // segments per strip-pair
#define SPAIRS 64     // 64-row strips: 128 strips -> 64 symmetric pairs
#define NWAVES (SPAIRS * NSEG)   // 3072
#define NBLK2  (NWAVES / 4)      // 768 blocks, 4 waves each
#define TPW    258    // 32-col tiles per strip-pair (256-2s + 2+2s)

typedef __attribute__((ext_vector_type(4))) float floatx4;

// ---------------------------------------------------------------------------
// Kernel 1: normalize -> fp8 e4m3 z (2 MiB), exact fp32 pos, zero-inits.
// (proven R8-R10: absmax 0.0)
// ---------------------------------------------------------------------------
__global__ __launch_bounds__(256) void norm_pos_kernel(
    const float* __restrict__ xi, const float* __restrict__ xj,
    unsigned char* __restrict__ z, float* __restrict__ pos,
    float* __restrict__ rowsum, float* __restrict__ out,
    unsigned int* __restrict__ counter) {
    int gt = blockIdx.x * 256 + threadIdx.x;
    if (gt < NROWS) rowsum[gt] = 0.f;
    if (gt == 0) { out[0] = 0.f; counter[0] = 0u; }

    int p    = blockIdx.x * 4 + (threadIdx.x >> 6);
    int lane = threadIdx.x & 63;
    float4 v1 = ((const float4*)(xi + (size_t)p * D))[lane];
    float4 v2 = ((const float4*)(xj + (size_t)p * D))[lane];
    float ss1 = v1.x * v1.x + v1.y * v1.y + v1.z * v1.z + v1.w * v1.w;
    float ss2 = v2.x * v2.x + v2.y * v2.y + v2.z * v2.z + v2.w * v2.w;
#pragma unroll
    for (int off = 32; off > 0; off >>= 1) {
        ss1 += __shfl_xor(ss1, off);
        ss2 += __shfl_xor(ss2, off);
    }
    float sc1 = 1.0f / fmaxf(sqrtf(ss1), 1e-12f);
    float sc2 = 1.0f / fmaxf(sqrtf(ss2), 1e-12f);

    float n1x = v1.x * sc1, n1y = v1.y * sc1, n1z = v1.z * sc1, n1w = v1.w * sc1;
    float n2x = v2.x * sc2, n2y = v2.y * sc2, n2z = v2.z * sc2, n2w = v2.w * sc2;

    float dp = n1x * n2x + n1y * n2y + n1z * n2z + n1w * n2w;
#pragma unroll
    for (int off = 32; off > 0; off >>= 1) dp += __shfl_xor(dp, off);
    if (lane == 0) { pos[p] = dp; pos[p + B_ROWS] = dp; }

    int q1 = __builtin_amdgcn_cvt_pk_fp8_f32(n1x, n1y, 0, false);
    q1     = __builtin_amdgcn_cvt_pk_fp8_f32(n1z, n1w, q1, true);
    int q2 = __builtin_amdgcn_cvt_pk_fp8_f32(n2x, n2y, 0, false);
    q2     = __builtin_amdgcn_cvt_pk_fp8_f32(n2z, n2w, q2, true);
    ((int*)(z + (size_t)p * D))[lane]            = q1;
    ((int*)(z + (size_t)(p + B_ROWS) * D))[lane] = q2;
}

// ---------------------------------------------------------------------------
// Kernel 2: symmetric sim+exp+rowsum, fp8 MFMA, WAVE-PRIVATE LDS (no barriers
// in the tile loop). Global wave wid = 4*blockIdx + w handles segment q of
// strip-pair s: strips (s, 127-s), 64 rows each; tiles are 32 cols x full K.
// A (64 rows x 256 K fp8 = 64 VGPRs) resident in registers per strip.
// B tile (32 cols x 256 K = 8 KB) in this wave's private LDS slice:
//   fetch:  instr j reads 1 KB contiguous (rows 4j..4j+3) -> 16 full lines.
//   layout: unit u(c16,col) = c16*32 + (col ^ (c16 & 7))   [16B units]
//   writes (lane t: col=4j+(t>>4), c16=t&15): quads (4j ^ (t&7)) -> 8x2 FREE
//   frag b64 (col=ni*16+lm, c16=kk*2+(lg>>1), half=(lg&1)*8): per-phase quads
//     ((ni*16+lm)^x) mod 8 spread by lm -> 8x2 FREE
// ds_write -> ds_read ordering within one wave is in-order (DS pipe): no sync.
// Diag-region tiles (cloc<2): predicate row==col. cloc>=2: mirror col-sums.
// ---------------------------------------------------------------------------
__global__ __launch_bounds__(256, 3) void sim_rowsum_kernel(
    const unsigned char* __restrict__ z, float* __restrict__ rowsum,
    const float* __restrict__ pos, unsigned int* __restrict__ counter,
    float* __restrict__ out) {
    __shared__ __align__(16) char Bsl[4][8192];   // 8 KB per wave slice
    __shared__ unsigned int done_s;
    __shared__ float sdata[4];

    const int tid  = threadIdx.x;
    const int lane = tid & 63;
    const int w    = tid >> 6;
    const int lm   = lane & 15;
    const int lg   = lane >> 4;

    char* myB = Bsl[w];

    const int wid = blockIdx.x * 4 + w;
    const int s   = wid / NSEG;            // strip-pair 0..63
    const int q   = wid % NSEG;            // segment 0..47
    const int L0  = 256 - 2 * s;           // tiles in strip s
    const int cb  = (q * TPW) / NSEG;
    const int ce  = ((q + 1) * TPW) / NSEG;

    // fetch/write geometry (lane t covers col=4j+(t>>4), c16=t&15 for instr j)
    const int fcol = lane >> 4;            // col offset within 4-row group
    const int fc16 = lane & 15;

    long long a[8][4];                     // A: 64 rows x 256 K fp8
    floatx4 acc[4][2];
    float rsacc[4][4];
    int4 pf[8];

#pragma unroll
    for (int mi = 0; mi < 4; mi++)
#pragma unroll
        for (int r = 0; r < 4; r++) rsacc[mi][r] = 0.f;

    auto decode = [&](int c, int& strip, int& colbase, int& cloc) {
        if (c < L0) { strip = s;       cloc = c; }
        else        { strip = 127 - s; cloc = c - L0; }
        colbase = strip * 64 + cloc * 32;
    };

    auto loadA = [&](int strip) {
#pragma unroll
        for (int kk = 0; kk < 8; kk++)
#pragma unroll
            for (int mi = 0; mi < 4; mi++)
                a[kk][mi] = *(const long long*)(
                    z + (size_t)(strip * 64 + mi * 16 + lm) * D + kk * 32 + lg * 8);
    };

    auto flushRs = [&](int strip) {
#pragma unroll
        for (int mi = 0; mi < 4; mi++)
#pragma unroll
            for (int r = 0; r < 4; r++) {
                float v = rsacc[mi][r];
                v += __shfl_xor(v, 1); v += __shfl_xor(v, 2);
                v += __shfl_xor(v, 4); v += __shfl_xor(v, 8);
                if (lm == 0)
                    atomicAdd(&rowsum[strip * 64 + mi * 16 + lg * 4 + r], v);
                rsacc[mi][r] = 0.f;
            }
    };

    auto fetch = [&](int colbase) {
        const unsigned char* p = z + (size_t)colbase * D + lane * 16;
#pragma unroll
        for (int j = 0; j < 8; j++)
            pf[j] = *(const int4*)(p + j * 1024);   // 1 KB contiguous per instr
    };
    auto writeB = [&]() {
#pragma unroll
        for (int j = 0; j < 8; j++) {
            const int col = 4 * j + fcol;
            const int u   = fc16 * 32 + (col ^ (fc16 & 7));
            *(int4*)(myB + u * 16) = pf[j];
        }
    };

    // ---- prologue ----
    int strip, colbase, cloc;
    decode(cb, strip, colbase, cloc);
    int curstrip = strip;
    fetch(colbase);
    writeB();
    loadA(strip);

    for (int c = cb; c < ce; c++) {
        decode(c, strip, colbase, cloc);

        const bool hn = (c + 1 < ce);
        if (hn) {                    // prefetch next tile into regs
            int ns, ncb2, ncl;
            decode(c + 1, ns, ncb2, ncl);
            fetch(ncb2);
        }
        if (strip != curstrip) {     // <=1 per wave
            flushRs(curstrip);
            loadA(strip);
            curstrip = strip;
        }

#pragma unroll
        for (int mi = 0; mi < 4; mi++)
#pragma unroll
            for (int ni = 0; ni < 2; ni++)
                acc[mi][ni] = (floatx4){0.f, 0.f, 0.f, 0.f};

        const int half = (lg & 1) * 8;
#pragma unroll
        for (int kk = 0; kk < 8; kk++) {
            const int c16 = kk * 2 + (lg >> 1);
            const int x   = c16 & 7;
            long long b0 = *(const long long*)(
                myB + (c16 * 32 + ((0 * 16 + lm) ^ x)) * 16 + half);
            long long b1 = *(const long long*)(
                myB + (c16 * 32 + ((1 * 16 + lm) ^ x)) * 16 + half);
#pragma unroll
            for (int mi = 0; mi < 4; mi++)
                acc[mi][0] = __builtin_amdgcn_mfma_f32_16x16x32_fp8_fp8(
                    a[kk][mi], b0, acc[mi][0], 0, 0, 0);
#pragma unroll
            for (int mi = 0; mi < 4; mi++)
                acc[mi][1] = __builtin_amdgcn_mfma_f32_16x16x32_fp8_fp8(
                    a[kk][mi], b1, acc[mi][1], 0, 0, 0);
        }

        // ---- epilogue: exp(2*sim) ----
        if (cloc < 2) {              // diag region: zero row==col
            const int rowb = strip * 64 + lg * 4;
#pragma unroll
            for (int mi = 0; mi < 4; mi++)
#pragma unroll
                for (int ni = 0; ni < 2; ni++) {
                    const int gcol = colbase + ni * 16 + lm;
#pragma unroll
                    for (int r = 0; r < 4; r++) {
                        const int grow = rowb + mi * 16 + r;
                        float e = (grow == gcol) ? 0.f
                                                 : __expf(2.0f * acc[mi][ni][r]);
                        rsacc[mi][r] += e;
                    }
                }
        } else {
            float cs0 = 0.f, cs1 = 0.f;
#pragma unroll
            for (int mi = 0; mi < 4; mi++)
#pragma unroll
                for (int r = 0; r < 4; r++) {
                    float e0 = __expf(2.0f * acc[mi][0][r]);
                    float e1 = __expf(2.0f * acc[mi][1][r]);
                    rsacc[mi][r] += e0 + e1;
                    cs0 += e0; cs1 += e1;
                }
            cs0 += __shfl_xor(cs0, 16); cs0 += __shfl_xor(cs0, 32);
            cs1 += __shfl_xor(cs1, 16); cs1 += __shfl_xor(cs1, 32);
            if (lane < 16) {
                atomicAdd(&rowsum[colbase + lane],      cs0);
                atomicAdd(&rowsum[colbase + 16 + lane], cs1);
            }
        }

        if (hn) writeB();            // in-order DS: prior reads already done
    }
    flushRs(curstrip);

    // ---- last-block-done: final loss ----
    __syncthreads();
    if (tid == 0) {
        __threadfence();
        done_s = atomicAdd(counter, 1u);
    }
    __syncthreads();
    if (done_s == (unsigned int)(NBLK2 - 1)) {
        __threadfence();
        float acc_l = 0.f;
#pragma unroll 4
        for (int r = tid; r < NROWS; r += 256) {
            float rsv = __hip_atomic_load(&rowsum[r], __ATOMIC_RELAXED,
                                          __HIP_MEMORY_SCOPE_AGENT);
            acc_l += -2.0f * pos[r] + logf(rsv);
        }
#pragma unroll
        for (int off = 32; off > 0; off >>= 1) acc_l += __shfl_xor(acc_l, off);
        if (lane == 0) sdata[w] = acc_l;
        __syncthreads();
        if (tid == 0)
            out[0] = (sdata[0] + sdata[1] + sdata[2] + sdata[3]) / (float)NROWS;
    }
}

// ---------------------------------------------------------------------------
extern "C" void kernel_launch(void* const* d_in, const int* in_sizes, int n_in,
                              void* d_out, int out_size, void* d_ws, size_t ws_size,
                              hipStream_t stream) {
    const float* xi = (const float*)d_in[0];
    const float* xj = (const float*)d_in[1];
    float* out      = (float*)d_out;

    char* ws         = (char*)d_ws;
    unsigned char* z = (unsigned char*)ws;                    // 2 MiB (fp8)
    float* rowsum    = (float*)(ws + (size_t)NROWS * D);      // 32 KiB
    float* pos       = rowsum + NROWS;                        // 32 KiB
    unsigned int* counter = (unsigned int*)(pos + NROWS);

    norm_pos_kernel<<<B_ROWS / 4, 256, 0, stream>>>(xi, xj, z, pos,
                                                    rowsum, out, counter);
    sim_rowsum_kernel<<<NBLK2, 256, 0, stream>>>(z, rowsum, pos, counter, out);
}